// Round 16
// baseline (524.781 us; speedup 1.0000x reference)
//
#include <hip/hip_runtime.h>
#include <cstddef>

// ---------------------------------------------------------------------------
// NestedTensorBlock (ViT block) on MI355X.
// D=1024, H=16, HD=64. Tokens: x1 8x1024 (tok 0..8191), x2 8x512 (tok 8192..12287).
// GEMMs (all bf16): BMx256 tile (BM=192 qkv/proj/fc2 -> grids 768/256/256 exact
// CU rounds; BM=256 fc1), BK=64, 8-phase, XOR-swizzled LDS, counted vmcnt,
// setprio, kk-outer. bf16 epilogues LDS-staged.
// Attention: Q-tile 256 (32 rows/wave — halves staging/barrier overhead per
// unit work), max-free softmax (scores bounded), 2-slot LDS dbuf, XCD-affine
// balanced mapping, T15 PV/SM overlap. launch_bounds(512,4) pins 128-VGPR.
// ---------------------------------------------------------------------------

typedef __bf16 b16x8 __attribute__((ext_vector_type(8)));
typedef float f32x4 __attribute__((ext_vector_type(4)));
typedef unsigned short u16x8 __attribute__((ext_vector_type(8)));
typedef unsigned short u16x4 __attribute__((ext_vector_type(4)));
typedef float f32x4v __attribute__((ext_vector_type(4)));

__device__ __forceinline__ unsigned short f2bf(float f) {
    unsigned int u = __builtin_bit_cast(unsigned int, f);
    return (unsigned short)((u + 0x7fffu + ((u >> 16) & 1u)) >> 16);
}
__device__ __forceinline__ unsigned short f2bf_trunc(float f) {
    return (unsigned short)(__builtin_bit_cast(unsigned int, f) >> 16);
}

__device__ __forceinline__ float exp2_f(float x) {
#if defined(__has_builtin)
#if __has_builtin(__builtin_amdgcn_exp2f)
    return __builtin_amdgcn_exp2f(x);
#else
    return exp2f(x);
#endif
#else
    return exp2f(x);
#endif
}

#define AS1C(p) ((const __attribute__((address_space(1))) void*)(p))
#define AS3(p)  ((__attribute__((address_space(3))) void*)(p))
#define FENCE() asm volatile("" ::: "memory")

// ---------------------------------------------------------------------------
// Weight transpose + f32->bf16:  in [K][N] f32  ->  out [N][K] bf16
// ---------------------------------------------------------------------------
__global__ __launch_bounds__(256) void wtrans_k(const float* __restrict__ in,
                                                unsigned short* __restrict__ out,
                                                int K, int N) {
    __shared__ float tile[32][33];
    int n0 = blockIdx.x << 5, k0 = blockIdx.y << 5;
    int tx = threadIdx.x & 31;
    int ty = threadIdx.x >> 5;  // 0..7
#pragma unroll
    for (int j = 0; j < 4; ++j)
        tile[ty + j * 8][tx] = in[(size_t)(k0 + ty + j * 8) * N + n0 + tx];
    __syncthreads();
#pragma unroll
    for (int j = 0; j < 4; ++j)
        out[(size_t)(n0 + ty + j * 8) * K + k0 + tx] = f2bf(tile[tx][ty + j * 8]);
}

// ---------------------------------------------------------------------------
// V transpose: qkv[tok][2048+c] (bf16) -> vT[c][tok], c in [0,1024)
// ---------------------------------------------------------------------------
__global__ __launch_bounds__(256) void vtrans_k(const unsigned short* __restrict__ qkv,
                                                unsigned short* __restrict__ vT) {
    __shared__ unsigned short tile[32][40];
    int tok0 = blockIdx.x << 5, c0 = blockIdx.y << 5;
    int tx = threadIdx.x & 31, ty = threadIdx.x >> 5;
#pragma unroll
    for (int j = 0; j < 4; ++j)
        tile[ty + j * 8][tx] = qkv[(size_t)(tok0 + ty + j * 8) * 3072 + 2048 + c0 + tx];
    __syncthreads();
#pragma unroll
    for (int j = 0; j < 4; ++j)
        vT[(size_t)(c0 + ty + j * 8) * 12288 + tok0 + tx] = tile[tx][ty + j * 8];
}

// ---------------------------------------------------------------------------
// LayerNorm: row in {srcA (row<split) | srcB}, 1024 cols -> bf16 out
// ---------------------------------------------------------------------------
__global__ __launch_bounds__(256) void ln_k(const float* __restrict__ srcA,
                                            const float* __restrict__ srcB, int split,
                                            const float* __restrict__ w,
                                            const float* __restrict__ b,
                                            unsigned short* __restrict__ out) {
    int row = blockIdx.x;
    const float* src = (row < split) ? srcA + (size_t)row * 1024
                                     : srcB + (size_t)(row - split) * 1024;
    int t = threadIdx.x;
    f32x4v v = *(const f32x4v*)(src + t * 4);
    float s = v[0] + v[1] + v[2] + v[3];
    float s2 = v[0] * v[0] + v[1] * v[1] + v[2] * v[2] + v[3] * v[3];
#pragma unroll
    for (int off = 1; off < 64; off <<= 1) {
        s += __shfl_xor(s, off);
        s2 += __shfl_xor(s2, off);
    }
    __shared__ float red[8];
    int wv4 = t >> 6;
    if ((t & 63) == 0) { red[wv4 * 2] = s; red[wv4 * 2 + 1] = s2; }
    __syncthreads();
    s = red[0] + red[2] + red[4] + red[6];
    s2 = red[1] + red[3] + red[5] + red[7];
    float mean = s * (1.0f / 1024.0f);
    float var = s2 * (1.0f / 1024.0f) - mean * mean;
    float rstd = rsqrtf(var + 1e-5f);
    f32x4v wv = *(const f32x4v*)(w + t * 4);
    f32x4v bv = *(const f32x4v*)(b + t * 4);
    u16x4 ov;
#pragma unroll
    for (int j = 0; j < 4; ++j) ov[j] = f2bf((v[j] - mean) * rstd * wv[j] + bv[j]);
    *(u16x4*)(out + (size_t)row * 1024 + t * 4) = ov;
}

// ---------------------------------------------------------------------------
// 8-phase BMx256 bf16 GEMM: C[M,NN] = A[M,K]*BT[NN,K]^T (+bias, epilogue EPI)
// 512 thr = 8 waves (2M x 4N); per-wave C = (BM/2)x64 = (BM/32)x4 16x16 frags.
// BK=64; LDS = 2 buf x (A BM*128B + B 32KB).
// EPI: 0 = store bf16 (qkv)          1 = out_f32 = x + gamma1*C (proj)
//      2 = store bf16(gelu(C)) (fc1) 3 = out_f32 += gamma2*C (fc2)
// ---------------------------------------------------------------------------
template <int BM, int K, int NN, int EPI>
__global__ __launch_bounds__(512, 1) void gemm3_k(
    const unsigned short* __restrict__ A, const unsigned short* __restrict__ BT,
    const float* __restrict__ bias, const float* __restrict__ scale,
    const float* __restrict__ rx1, const float* __restrict__ rx2,
    float* __restrict__ outf, unsigned short* __restrict__ outb) {
    constexpr int NT = K / 64;
    constexpr int ntn = NN >> 8;
    constexpr int GA = BM / 64;
    constexpr int NFR = BM / 32;
    constexpr int HALF = NFR / 2;
    constexpr int ABUF = BM * 128;
    constexpr int STRIDE = ABUF + 32768;
    __shared__ char lds[2 * STRIDE];
    const int t = threadIdx.x;
    const int lane = t & 63, w = t >> 6, lr = lane & 15, lg = lane >> 4;
    const int wm = w >> 2, wn = w & 3;
    const int nwg = gridDim.x;
    const int bid = blockIdx.x;
    const int swz = (bid & 7) * (nwg >> 3) + (bid >> 3);
    const int m0 = (swz / ntn) * BM;
    const int n0 = (swz % ntn) << 8;

    const int srow = t >> 3;
    const int scol = ((t & 7) ^ (srow & 7)) * 8;  // shorts
    const unsigned short* ga = A + (size_t)(m0 + srow) * K + scol;
    const unsigned short* gb = BT + (size_t)(n0 + srow) * K + scol;

    f32x4 acc[NFR][4] = {};
    b16x8 af[HALF][2], b01[2][2], b23[2][2];

    auto ISSUE_A = [&](int tile, int g) {
        char* dst = lds + (tile & 1) * STRIDE + g * 8192 + t * 16;
        __builtin_amdgcn_global_load_lds(AS1C(ga + (size_t)(g * 64) * K + tile * 64),
                                         AS3(dst), 16, 0, 0);
    };
    auto ISSUE_B = [&](int tile, int g) {
        char* dst = lds + (tile & 1) * STRIDE + ABUF + g * 8192 + t * 16;
        __builtin_amdgcn_global_load_lds(AS1C(gb + (size_t)(g * 64) * K + tile * 64),
                                         AS3(dst), 16, 0, 0);
    };

    const int cs0 = (lg ^ (lr & 7)) * 16;
    const int cs1 = ((4 + lg) ^ (lr & 7)) * 16;

    auto RD_A = [&](const char* buf, int mg) {
#pragma unroll
        for (int mi = 0; mi < HALF; ++mi) {
            const char* p = buf + (wm * (BM / 2) + (mg + mi) * 16 + lr) * 128;
            af[mi][0] = *(const b16x8*)(p + cs0);
            af[mi][1] = *(const b16x8*)(p + cs1);
        }
    };
    auto RD_B = [&](const char* buf, b16x8 (*bf)[2], int ng) {
#pragma unroll
        for (int ni = 0; ni < 2; ++ni) {
            const char* p = buf + ABUF + (wn * 64 + (ng + ni) * 16 + lr) * 128;
            bf[ni][0] = *(const b16x8*)(p + cs0);
            bf[ni][1] = *(const b16x8*)(p + cs1);
        }
    };
    auto MM = [&](int mg, b16x8 (*bf)[2], int ng) {
        __builtin_amdgcn_s_setprio(1);
#pragma unroll
        for (int kk = 0; kk < 2; ++kk)
#pragma unroll
            for (int mi = 0; mi < HALF; ++mi)
#pragma unroll
                for (int ni = 0; ni < 2; ++ni)
                    acc[mg + mi][ng + ni] = __builtin_amdgcn_mfma_f32_16x16x32_bf16(
                        af[mi][kk], bf[ni][kk], acc[mg + mi][ng + ni], 0, 0, 0);
        __builtin_amdgcn_s_setprio(0);
    };
    auto WAIT_GA = [&]() {
        if constexpr (GA == 4) asm volatile("s_waitcnt vmcnt(4)" ::: "memory");
        else                   asm volatile("s_waitcnt vmcnt(3)" ::: "memory");
    };

#pragma unroll
    for (int g = 0; g < GA; ++g) ISSUE_A(0, g);
#pragma unroll
    for (int g = 0; g < 4; ++g) ISSUE_B(0, g);
#pragma unroll
    for (int g = 0; g < GA; ++g) ISSUE_A(1, g);
    WAIT_GA();
    __builtin_amdgcn_s_barrier();
    FENCE();

    for (int kt = 0; kt < NT; ++kt) {
        const char* buf = lds + (kt & 1) * STRIDE;
        RD_A(buf, 0); RD_B(buf, b01, 0);
        if (kt + 1 < NT) { ISSUE_B(kt + 1, 0); ISSUE_B(kt + 1, 1); }
        __builtin_amdgcn_s_barrier(); FENCE();
        MM(0, b01, 0);
        __builtin_amdgcn_s_barrier(); FENCE();
        RD_B(buf, b23, 2);
        if (kt + 1 < NT) { ISSUE_B(kt + 1, 2); ISSUE_B(kt + 1, 3); }
        __builtin_amdgcn_s_barrier(); FENCE();
        MM(0, b23, 2);
        __builtin_amdgcn_s_barrier(); FENCE();
        RD_A(buf, HALF);
        __builtin_amdgcn_s_barrier(); FENCE();
        MM(HALF, b23, 2);
        __builtin_amdgcn_s_barrier(); FENCE();
        if (kt + 2 < NT) {
#pragma unroll
            for (int g = 0; g < GA; ++g) ISSUE_A(kt + 2, g);
        }
        __builtin_amdgcn_s_barrier(); FENCE();
        MM(HALF, b01, 0);
        if (kt + 1 < NT) {
            if (kt + 2 < NT) WAIT_GA();
            else             asm volatile("s_waitcnt vmcnt(0)" ::: "memory");
            __builtin_amdgcn_s_barrier(); FENCE();
        }
    }

    if (EPI == 0 || EPI == 2) {
        __syncthreads();
        char* clb = lds;
        const int rl0 = wm * (BM / 2) + lg * 4;
        const int cl0 = wn * 64 + lr;
#pragma unroll
        for (int n = 0; n < 4; ++n) {
            const int col_l = cl0 + n * 16;
            const float bval = bias[n0 + col_l];
            const int colByte = col_l * 2;
            const int within = colByte & 15;
            const int chunk = colByte >> 4;
#pragma unroll
            for (int m = 0; m < NFR; ++m) {
#pragma unroll
                for (int r = 0; r < 4; ++r) {
                    float c = acc[m][n][r] + bval;
                    if (EPI == 2) {
                        float u = c * (c * c * 0.044715f + 1.0f) * 1.5957691216057308f;
                        c = c * __builtin_amdgcn_rcpf(1.0f + __expf(-u));
                    }
                    const int row_l = rl0 + m * 16 + r;
                    *(unsigned short*)(clb + row_l * 512 +
                                       (((chunk ^ (row_l & 7)) << 4) | within)) = f2bf(c);
                }
            }
        }
        __syncthreads();
#pragma unroll
        for (int it = 0; it < BM / 16; ++it) {
            int idx = it * 512 + t;
            int row = idx >> 5, ch = idx & 31;
            u16x8 v = *(const u16x8*)(clb + row * 512 + ((ch ^ (row & 7)) << 4));
            *(u16x8*)(outb + (size_t)(m0 + row) * NN + n0 + ch * 8) = v;
        }
    } else {
        const int rbase = m0 + wm * (BM / 2) + lg * 4;
        const int cbase = n0 + wn * 64 + lr;
#pragma unroll
        for (int n = 0; n < 4; ++n) {
            int col = cbase + n * 16;
            float bval = bias[col];
            float sval = scale[col];
#pragma unroll
            for (int m = 0; m < NFR; ++m) {
                int row = rbase + m * 16;
#pragma unroll
                for (int r = 0; r < 4; ++r) {
                    float c = acc[m][n][r] + bval;
                    size_t idx = (size_t)(row + r) * NN + col;
                    if (EPI == 1) {
                        float xv = (row + r < 8192) ? rx1[idx] : rx2[idx - (size_t)8192 * 1024];
                        outf[idx] = xv + sval * c;
                    } else {
                        outf[idx] += sval * c;
                    }
                }
            }
        }
    }
}

// ---------------------------------------------------------------------------
// Flash attention, Q-tile 256 (32 q-rows/wave), max-free softmax:
// one block = (seq, head, 256-row Q tile), 8 waves, 2-slot K/V LDS dbuf,
// XCD-affine balanced mapping (per XCD: 64 long + 32 short blocks).
// Per KV-tile: QK 16 MFMA, P=exp2 direct (32), PV 16 MFMA — staging/barriers
// amortized 2x vs Q-tile 128. T15: PV(kt) overlaps SM(kt+1).
// ---------------------------------------------------------------------------
__global__ __launch_bounds__(512, 4) void attn_k(const unsigned short* __restrict__ qkv,
                                                 const unsigned short* __restrict__ vT,
                                                 unsigned short* __restrict__ aout) {
    __shared__ char sbuf[32768 + 8 * 32 * 72 * 2];  // K/V slots 32KB + P 36KB
    char* sKb = sbuf;             // [2][8192]
    char* sVb = sbuf + 16384;     // [2][8192]
    unsigned short* sP = (unsigned short*)(sbuf + 32768);  // [8][32*72]
    const int xcd = blockIdx.x & 7;
    const int idx = blockIdx.x >> 3;  // 0..95 per XCD
    int seq0, S, h, qt;
    if (idx < 64) {           // x1: seq = xcd; 16 heads x 4 qtiles(256)
        h = idx & 15; qt = idx >> 4; seq0 = xcd << 10; S = 1024;
    } else {                  // x2: seq = xcd; 16 heads x 2 qtiles
        int j = idx - 64;
        h = j & 15; qt = j >> 4; seq0 = 8192 + (xcd << 9); S = 512;
    }
    int t = threadIdx.x, lane = t & 63, w = t >> 6, lr = lane & 15, lg = lane >> 4;
    int tok0 = seq0 + qt * 256;
    const size_t hoff = (size_t)h * 64;

    const int srow = t >> 3;
    const int sc = ((t & 7) ^ (srow & 7)) * 8;
    const unsigned short* kg = qkv + (size_t)(seq0 + srow) * 3072 + 1024 + hoff + sc;
    const unsigned short* vg = vT + (size_t)(hoff + srow) * 12288 + seq0 + sc;

    // Q fragments: per wave rows tok0 + w*32 + g*16 + lr, g = 0,1
    b16x8 aq[2][2];
#pragma unroll
    for (int g = 0; g < 2; ++g) {
        const unsigned short* qb = qkv + (size_t)(tok0 + w * 32 + g * 16 + lr) * 3072 + hoff;
        aq[g][0] = *(const b16x8*)(qb + lg * 8);
        aq[g][1] = *(const b16x8*)(qb + 32 + lg * 8);
    }

    auto STAGE = [&](int kt) {
        int slot = kt & 1;
        __builtin_amdgcn_global_load_lds(AS1C(kg + (size_t)(kt << 6) * 3072),
                                         AS3(sKb + slot * 8192 + t * 16), 16, 0, 0);
        __builtin_amdgcn_global_load_lds(AS1C(vg + (kt << 6)),
                                         AS3(sVb + slot * 8192 + t * 16), 16, 0, 0);
    };

    const int swz0 = (lg ^ (lr & 7)) * 16;
    const int swz1 = ((4 + lg) ^ (lr & 7)) * 16;
    const float SC = 0.18033688f;  // 0.125 * log2(e)

    float lsum[2][4] = {};
    f32x4 o[2][4] = {};
    unsigned short* sPw = sP + w * 32 * 72;
    const int nkv = S >> 6;

    auto QK = [&](int kt, f32x4 (&s)[2][4]) {
        const char* kb = sKb + (kt & 1) * 8192;
#pragma unroll
        for (int n = 0; n < 4; ++n) {
            const char* kr = kb + (n * 16 + lr) * 128;
            b16x8 bk0 = *(const b16x8*)(kr + swz0);
            b16x8 bk1 = *(const b16x8*)(kr + swz1);
#pragma unroll
            for (int g = 0; g < 2; ++g) {
                f32x4 z = {};
                z = __builtin_amdgcn_mfma_f32_16x16x32_bf16(aq[g][0], bk0, z, 0, 0, 0);
                z = __builtin_amdgcn_mfma_f32_16x16x32_bf16(aq[g][1], bk1, z, 0, 0, 0);
                s[g][n] = z * SC;
            }
        }
    };
    // max-free: P = exp2(s); per-lane partial row sums; P->LDS->A-frags
    auto SM = [&](f32x4 (&s)[2][4], b16x8 (&ap)[2][2]) {
#pragma unroll
        for (int g = 0; g < 2; ++g) {
            float p[4][4];
#pragma unroll
            for (int n = 0; n < 4; ++n)
#pragma unroll
                for (int r = 0; r < 4; ++r)
                    p[n][r] = exp2_f(s[g][n][r]);
#pragma unroll
            for (int r = 0; r < 4; ++r)
                lsum[g][r] += (p[0][r] + p[1][r]) + (p[2][r] + p[3][r]);
#pragma unroll
            for (int r = 0; r < 4; ++r)
#pragma unroll
                for (int n = 0; n < 4; ++n)
                    sPw[(g * 16 + lg * 4 + r) * 72 + n * 16 + lr] = f2bf_trunc(p[n][r]);
        }
#pragma unroll
        for (int g = 0; g < 2; ++g) {
            ap[g][0] = *(const b16x8*)(&sPw[(g * 16 + lr) * 72 + lg * 8]);
            ap[g][1] = *(const b16x8*)(&sPw[(g * 16 + lr) * 72 + 32 + lg * 8]);
        }
    };

    // prologue
    STAGE(0);
    if (nkv > 1) STAGE(1);
    asm volatile("s_waitcnt vmcnt(0)" ::: "memory");
    __builtin_amdgcn_s_barrier();
    FENCE();
    f32x4 s0[2][4];
    QK(0, s0);
    b16x8 ap[2][2];
    SM(s0, ap);

    for (int kt = 0; kt < nkv; ++kt) {
        const char* vb = sVb + (kt & 1) * 8192;
        b16x8 bv0[4], bv1[4];
#pragma unroll
        for (int n = 0; n < 4; ++n) {
            const char* vr = vb + (n * 16 + lr) * 128;
            bv0[n] = *(const b16x8*)(vr + swz0);
            bv1[n] = *(const b16x8*)(vr + swz1);
        }
        f32x4 s2[2][4];
        if (kt + 1 < nkv) QK(kt + 1, s2);
        asm volatile("s_waitcnt lgkmcnt(0)" ::: "memory");
        __builtin_amdgcn_s_barrier();
        FENCE();
        if (kt + 2 < nkv) STAGE(kt + 2);
        // PV(kt) [MFMA] overlapped with SM(kt+1) [VALU]
#pragma unroll
        for (int n = 0; n < 4; ++n) {
#pragma unroll
            for (int g = 0; g < 2; ++g) {
                o[g][n] = __builtin_amdgcn_mfma_f32_16x16x32_bf16(ap[g][0], bv0[n], o[g][n], 0, 0, 0);
                o[g][n] = __builtin_amdgcn_mfma_f32_16x16x32_bf16(ap[g][1], bv1[n], o[g][n], 0, 0, 0);
            }
        }
        if (kt + 1 < nkv) {
            SM(s2, ap);
            asm volatile("s_waitcnt vmcnt(0)" ::: "memory");
            __builtin_amdgcn_s_barrier();
            FENCE();
        }
    }
    // final row-sum reduction (once) + LDS-staged coalesced output (256x64 bf16
    // = 32 KB, reuses the K/V slot region).
#pragma unroll
    for (int g = 0; g < 2; ++g)
#pragma unroll
        for (int r = 0; r < 4; ++r) {
            lsum[g][r] += __shfl_xor(lsum[g][r], 1);
            lsum[g][r] += __shfl_xor(lsum[g][r], 2);
            lsum[g][r] += __shfl_xor(lsum[g][r], 4);
            lsum[g][r] += __shfl_xor(lsum[g][r], 8);
        }
    __syncthreads();
    char* ob = sbuf;
#pragma unroll
    for (int g = 0; g < 2; ++g)
#pragma unroll
        for (int r = 0; r < 4; ++r) {
            float inv = __builtin_amdgcn_rcpf(lsum[g][r]);
            const int row_l = w * 32 + g * 16 + lg * 4 + r;
#pragma unroll
            for (int n = 0; n < 4; ++n) {
                const int colByte = (n * 16 + lr) * 2;
                *(unsigned short*)(ob + row_l * 128 +
                                   ((((colByte >> 4) ^ (row_l & 7)) << 4) | (colByte & 15))) =
                    f2bf(o[g][n][r] * inv);
            }
        }
    __syncthreads();
#pragma unroll
    for (int it = 0; it < 4; ++it) {
        int idx2 = it * 512 + t;
        int row = idx2 >> 3, ch = idx2 & 7;
        u16x8 v = *(const u16x8*)(ob + row * 128 + ((ch ^ (row & 7)) << 4));
        *(u16x8*)(aout + (size_t)(tok0 + row) * 1024 + hoff + ch * 8) = v;
    }
}

// ---------------------------------------------------------------------------
// Launch
// ---------------------------------------------------------------------------
extern "C" void kernel_launch(void* const* d_in, const int* in_sizes, int n_in,
                              void* d_out, int out_size, void* d_ws, size_t ws_size,
                              hipStream_t stream) {
    const float* x1     = (const float*)d_in[0];
    const float* x2     = (const float*)d_in[1];
    const float* w_qkv  = (const float*)d_in[2];
    const float* b_qkv  = (const float*)d_in[3];
    const float* w_proj = (const float*)d_in[4];
    const float* b_proj = (const float*)d_in[5];
    const float* ln1w   = (const float*)d_in[6];
    const float* ln1b   = (const float*)d_in[7];
    const float* ln2w   = (const float*)d_in[8];
    const float* ln2b   = (const float*)d_in[9];
    const float* w_fc1  = (const float*)d_in[10];
    const float* b_fc1  = (const float*)d_in[11];
    const float* w_fc2  = (const float*)d_in[12];
    const float* b_fc2  = (const float*)d_in[13];
    const float* gamma1 = (const float*)d_in[14];
    const float* gamma2 = (const float*)d_in[15];
    float* out = (float*)d_out;
    char* ws = (char*)d_ws;

    // Workspace layout (144 MiB total)
    unsigned short* wqkvT  = (unsigned short*)(ws);              //  6291456 B
    unsigned short* wprojT = (unsigned short*)(ws + 6291456);    //  2097152 B
    unsigned short* wfc1T  = (unsigned short*)(ws + 8388608);    //  8388608 B
    unsigned short* wfc2T  = (unsigned short*)(ws + 16777216);   //  8388608 B
    unsigned short* lnbuf  = (unsigned short*)(ws + 25165824);   // 25165824 B (also vT later)
    unsigned short* qkvbuf = (unsigned short*)(ws + 50331648);   // 75497472 B
    unsigned short* attnbuf= (unsigned short*)(ws + 125829120);  // 25165824 B
    unsigned short* actbuf = (unsigned short*)(ws + 50331648);   // aliases qkv+attn (dead by then)
    unsigned short* vTbuf  = lnbuf;                              // 1024 x 12288 bf16

    wtrans_k<<<dim3(96, 32), 256, 0, stream>>>(w_qkv, wqkvT, 1024, 3072);
    wtrans_k<<<dim3(32, 32), 256, 0, stream>>>(w_proj, wprojT, 1024, 1024);
    wtrans_k<<<dim3(128, 32), 256, 0, stream>>>(w_fc1, wfc1T, 1024, 4096);
    wtrans_k<<<dim3(32, 128), 256, 0, stream>>>(w_fc2, wfc2T, 4096, 1024);
    ln_k<<<12288, 256, 0, stream>>>(x1, x2, 8192, ln1w, ln1b, lnbuf);
    // qkv: 64 m-tiles x 12 n-tiles = 768 blocks (3 exact CU rounds)
    gemm3_k<192, 1024, 3072, 0><<<768, 512, 0, stream>>>(lnbuf, wqkvT, b_qkv, nullptr,
                                                         nullptr, nullptr, nullptr, qkvbuf);
    vtrans_k<<<dim3(384, 32), 256, 0, stream>>>(qkvbuf, vTbuf);
    // attention: Q-tile 256 -> 8 xcd x (64 + 32) = 768 blocks
    attn_k<<<768, 512, 0, stream>>>(qkvbuf, vTbuf, attnbuf);
    // proj: 64 x 4 = 256 blocks (1 exact round)
    gemm3_k<192, 1024, 1024, 1><<<256, 512, 0, stream>>>(attnbuf, wprojT, b_proj, gamma1,
                                                         x1, x2, out, nullptr);
    ln_k<<<12288, 256, 0, stream>>>(out, out + (size_t)8192 * 1024, 8192, ln2w, ln2b, lnbuf);
    // fc1: BM=256 -> 48 x 16 = 768 blocks (3 exact rounds)
    gemm3_k<256, 1024, 4096, 2><<<768, 512, 0, stream>>>(lnbuf, wfc1T, b_fc1, nullptr,
                                                         nullptr, nullptr, nullptr, actbuf);
    // fc2: 64 x 4 = 256 blocks (1 exact round)
    gemm3_k<192, 4096, 1024, 3><<<256, 512, 0, stream>>>(actbuf, wfc2T, b_fc2, gamma2,
                                                         nullptr, nullptr, out, nullptr);
}

// Round 17
// 503.483 us; speedup vs baseline: 1.0423x; 1.0423x over previous
//
#include <hip/hip_runtime.h>
#include <cstddef>

// ---------------------------------------------------------------------------
// NestedTensorBlock (ViT block) on MI355X — round-15 best configuration.
// D=1024, H=16, HD=64. Tokens: x1 8x1024 (tok 0..8191), x2 8x512 (tok 8192..12287).
// GEMMs (all bf16): BMx256 tile (BM=192 qkv/proj/fc2 -> grids 768/256/256 exact
// CU rounds; BM=256 fc1), BK=64, 8-phase, XOR-swizzled LDS, counted vmcnt,
// setprio, kk-outer. bf16 epilogues LDS-staged.
// Attention: Q-tile 128 (8 waves, 52 VGPR, 2 blocks/CU), max-free softmax
// (scores bounded -> P = exp2(s*SC) directly, row-sum reduced once post-loop),
// 2-slot LDS dbuf, XCD-affine balanced mapping, T15 PV/SM overlap.
// ---------------------------------------------------------------------------

typedef __bf16 b16x8 __attribute__((ext_vector_type(8)));
typedef float f32x4 __attribute__((ext_vector_type(4)));
typedef unsigned short u16x8 __attribute__((ext_vector_type(8)));
typedef unsigned short u16x4 __attribute__((ext_vector_type(4)));
typedef float f32x4v __attribute__((ext_vector_type(4)));

__device__ __forceinline__ unsigned short f2bf(float f) {
    unsigned int u = __builtin_bit_cast(unsigned int, f);
    return (unsigned short)((u + 0x7fffu + ((u >> 16) & 1u)) >> 16);
}
__device__ __forceinline__ unsigned short f2bf_trunc(float f) {
    return (unsigned short)(__builtin_bit_cast(unsigned int, f) >> 16);
}

__device__ __forceinline__ float exp2_f(float x) {
#if defined(__has_builtin)
#if __has_builtin(__builtin_amdgcn_exp2f)
    return __builtin_amdgcn_exp2f(x);
#else
    return exp2f(x);
#endif
#else
    return exp2f(x);
#endif
}

#define AS1C(p) ((const __attribute__((address_space(1))) void*)(p))
#define AS3(p)  ((__attribute__((address_space(3))) void*)(p))
#define FENCE() asm volatile("" ::: "memory")

// ---------------------------------------------------------------------------
// Weight transpose + f32->bf16:  in [K][N] f32  ->  out [N][K] bf16
// ---------------------------------------------------------------------------
__global__ __launch_bounds__(256) void wtrans_k(const float* __restrict__ in,
                                                unsigned short* __restrict__ out,
                                                int K, int N) {
    __shared__ float tile[32][33];
    int n0 = blockIdx.x << 5, k0 = blockIdx.y << 5;
    int tx = threadIdx.x & 31;
    int ty = threadIdx.x >> 5;  // 0..7
#pragma unroll
    for (int j = 0; j < 4; ++j)
        tile[ty + j * 8][tx] = in[(size_t)(k0 + ty + j * 8) * N + n0 + tx];
    __syncthreads();
#pragma unroll
    for (int j = 0; j < 4; ++j)
        out[(size_t)(n0 + ty + j * 8) * K + k0 + tx] = f2bf(tile[tx][ty + j * 8]);
}

// ---------------------------------------------------------------------------
// V transpose: qkv[tok][2048+c] (bf16) -> vT[c][tok], c in [0,1024)
// ---------------------------------------------------------------------------
__global__ __launch_bounds__(256) void vtrans_k(const unsigned short* __restrict__ qkv,
                                                unsigned short* __restrict__ vT) {
    __shared__ unsigned short tile[32][40];
    int tok0 = blockIdx.x << 5, c0 = blockIdx.y << 5;
    int tx = threadIdx.x & 31, ty = threadIdx.x >> 5;
#pragma unroll
    for (int j = 0; j < 4; ++j)
        tile[ty + j * 8][tx] = qkv[(size_t)(tok0 + ty + j * 8) * 3072 + 2048 + c0 + tx];
    __syncthreads();
#pragma unroll
    for (int j = 0; j < 4; ++j)
        vT[(size_t)(c0 + ty + j * 8) * 12288 + tok0 + tx] = tile[tx][ty + j * 8];
}

// ---------------------------------------------------------------------------
// LayerNorm: row in {srcA (row<split) | srcB}, 1024 cols -> bf16 out
// ---------------------------------------------------------------------------
__global__ __launch_bounds__(256) void ln_k(const float* __restrict__ srcA,
                                            const float* __restrict__ srcB, int split,
                                            const float* __restrict__ w,
                                            const float* __restrict__ b,
                                            unsigned short* __restrict__ out) {
    int row = blockIdx.x;
    const float* src = (row < split) ? srcA + (size_t)row * 1024
                                     : srcB + (size_t)(row - split) * 1024;
    int t = threadIdx.x;
    f32x4v v = *(const f32x4v*)(src + t * 4);
    float s = v[0] + v[1] + v[2] + v[3];
    float s2 = v[0] * v[0] + v[1] * v[1] + v[2] * v[2] + v[3] * v[3];
#pragma unroll
    for (int off = 1; off < 64; off <<= 1) {
        s += __shfl_xor(s, off);
        s2 += __shfl_xor(s2, off);
    }
    __shared__ float red[8];
    int wv4 = t >> 6;
    if ((t & 63) == 0) { red[wv4 * 2] = s; red[wv4 * 2 + 1] = s2; }
    __syncthreads();
    s = red[0] + red[2] + red[4] + red[6];
    s2 = red[1] + red[3] + red[5] + red[7];
    float mean = s * (1.0f / 1024.0f);
    float var = s2 * (1.0f / 1024.0f) - mean * mean;
    float rstd = rsqrtf(var + 1e-5f);
    f32x4v wv = *(const f32x4v*)(w + t * 4);
    f32x4v bv = *(const f32x4v*)(b + t * 4);
    u16x4 ov;
#pragma unroll
    for (int j = 0; j < 4; ++j) ov[j] = f2bf((v[j] - mean) * rstd * wv[j] + bv[j]);
    *(u16x4*)(out + (size_t)row * 1024 + t * 4) = ov;
}

// ---------------------------------------------------------------------------
// 8-phase BMx256 bf16 GEMM: C[M,NN] = A[M,K]*BT[NN,K]^T (+bias, epilogue EPI)
// 512 thr = 8 waves (2M x 4N); per-wave C = (BM/2)x64 = (BM/32)x4 16x16 frags.
// BK=64; LDS = 2 buf x (A BM*128B + B 32KB).
// EPI: 0 = store bf16 (qkv)          1 = out_f32 = x + gamma1*C (proj)
//      2 = store bf16(gelu(C)) (fc1) 3 = out_f32 += gamma2*C (fc2)
// ---------------------------------------------------------------------------
template <int BM, int K, int NN, int EPI>
__global__ __launch_bounds__(512, 1) void gemm3_k(
    const unsigned short* __restrict__ A, const unsigned short* __restrict__ BT,
    const float* __restrict__ bias, const float* __restrict__ scale,
    const float* __restrict__ rx1, const float* __restrict__ rx2,
    float* __restrict__ outf, unsigned short* __restrict__ outb) {
    constexpr int NT = K / 64;
    constexpr int ntn = NN >> 8;
    constexpr int GA = BM / 64;
    constexpr int NFR = BM / 32;
    constexpr int HALF = NFR / 2;
    constexpr int ABUF = BM * 128;
    constexpr int STRIDE = ABUF + 32768;
    __shared__ char lds[2 * STRIDE];
    const int t = threadIdx.x;
    const int lane = t & 63, w = t >> 6, lr = lane & 15, lg = lane >> 4;
    const int wm = w >> 2, wn = w & 3;
    const int nwg = gridDim.x;
    const int bid = blockIdx.x;
    const int swz = (bid & 7) * (nwg >> 3) + (bid >> 3);
    const int m0 = (swz / ntn) * BM;
    const int n0 = (swz % ntn) << 8;

    const int srow = t >> 3;
    const int scol = ((t & 7) ^ (srow & 7)) * 8;  // shorts
    const unsigned short* ga = A + (size_t)(m0 + srow) * K + scol;
    const unsigned short* gb = BT + (size_t)(n0 + srow) * K + scol;

    f32x4 acc[NFR][4] = {};
    b16x8 af[HALF][2], b01[2][2], b23[2][2];

    auto ISSUE_A = [&](int tile, int g) {
        char* dst = lds + (tile & 1) * STRIDE + g * 8192 + t * 16;
        __builtin_amdgcn_global_load_lds(AS1C(ga + (size_t)(g * 64) * K + tile * 64),
                                         AS3(dst), 16, 0, 0);
    };
    auto ISSUE_B = [&](int tile, int g) {
        char* dst = lds + (tile & 1) * STRIDE + ABUF + g * 8192 + t * 16;
        __builtin_amdgcn_global_load_lds(AS1C(gb + (size_t)(g * 64) * K + tile * 64),
                                         AS3(dst), 16, 0, 0);
    };

    const int cs0 = (lg ^ (lr & 7)) * 16;
    const int cs1 = ((4 + lg) ^ (lr & 7)) * 16;

    auto RD_A = [&](const char* buf, int mg) {
#pragma unroll
        for (int mi = 0; mi < HALF; ++mi) {
            const char* p = buf + (wm * (BM / 2) + (mg + mi) * 16 + lr) * 128;
            af[mi][0] = *(const b16x8*)(p + cs0);
            af[mi][1] = *(const b16x8*)(p + cs1);
        }
    };
    auto RD_B = [&](const char* buf, b16x8 (*bf)[2], int ng) {
#pragma unroll
        for (int ni = 0; ni < 2; ++ni) {
            const char* p = buf + ABUF + (wn * 64 + (ng + ni) * 16 + lr) * 128;
            bf[ni][0] = *(const b16x8*)(p + cs0);
            bf[ni][1] = *(const b16x8*)(p + cs1);
        }
    };
    auto MM = [&](int mg, b16x8 (*bf)[2], int ng) {
        __builtin_amdgcn_s_setprio(1);
#pragma unroll
        for (int kk = 0; kk < 2; ++kk)
#pragma unroll
            for (int mi = 0; mi < HALF; ++mi)
#pragma unroll
                for (int ni = 0; ni < 2; ++ni)
                    acc[mg + mi][ng + ni] = __builtin_amdgcn_mfma_f32_16x16x32_bf16(
                        af[mi][kk], bf[ni][kk], acc[mg + mi][ng + ni], 0, 0, 0);
        __builtin_amdgcn_s_setprio(0);
    };
    auto WAIT_GA = [&]() {
        if constexpr (GA == 4) asm volatile("s_waitcnt vmcnt(4)" ::: "memory");
        else                   asm volatile("s_waitcnt vmcnt(3)" ::: "memory");
    };

#pragma unroll
    for (int g = 0; g < GA; ++g) ISSUE_A(0, g);
#pragma unroll
    for (int g = 0; g < 4; ++g) ISSUE_B(0, g);
#pragma unroll
    for (int g = 0; g < GA; ++g) ISSUE_A(1, g);
    WAIT_GA();
    __builtin_amdgcn_s_barrier();
    FENCE();

    for (int kt = 0; kt < NT; ++kt) {
        const char* buf = lds + (kt & 1) * STRIDE;
        RD_A(buf, 0); RD_B(buf, b01, 0);
        if (kt + 1 < NT) { ISSUE_B(kt + 1, 0); ISSUE_B(kt + 1, 1); }
        __builtin_amdgcn_s_barrier(); FENCE();
        MM(0, b01, 0);
        __builtin_amdgcn_s_barrier(); FENCE();
        RD_B(buf, b23, 2);
        if (kt + 1 < NT) { ISSUE_B(kt + 1, 2); ISSUE_B(kt + 1, 3); }
        __builtin_amdgcn_s_barrier(); FENCE();
        MM(0, b23, 2);
        __builtin_amdgcn_s_barrier(); FENCE();
        RD_A(buf, HALF);
        __builtin_amdgcn_s_barrier(); FENCE();
        MM(HALF, b23, 2);
        __builtin_amdgcn_s_barrier(); FENCE();
        if (kt + 2 < NT) {
#pragma unroll
            for (int g = 0; g < GA; ++g) ISSUE_A(kt + 2, g);
        }
        __builtin_amdgcn_s_barrier(); FENCE();
        MM(HALF, b01, 0);
        if (kt + 1 < NT) {
            if (kt + 2 < NT) WAIT_GA();
            else             asm volatile("s_waitcnt vmcnt(0)" ::: "memory");
            __builtin_amdgcn_s_barrier(); FENCE();
        }
    }

    if (EPI == 0 || EPI == 2) {
        __syncthreads();
        char* clb = lds;
        const int rl0 = wm * (BM / 2) + lg * 4;
        const int cl0 = wn * 64 + lr;
#pragma unroll
        for (int n = 0; n < 4; ++n) {
            const int col_l = cl0 + n * 16;
            const float bval = bias[n0 + col_l];
            const int colByte = col_l * 2;
            const int within = colByte & 15;
            const int chunk = colByte >> 4;
#pragma unroll
            for (int m = 0; m < NFR; ++m) {
#pragma unroll
                for (int r = 0; r < 4; ++r) {
                    float c = acc[m][n][r] + bval;
                    if (EPI == 2) {
                        float u = c * (c * c * 0.044715f + 1.0f) * 1.5957691216057308f;
                        c = c * __builtin_amdgcn_rcpf(1.0f + __expf(-u));
                    }
                    const int row_l = rl0 + m * 16 + r;
                    *(unsigned short*)(clb + row_l * 512 +
                                       (((chunk ^ (row_l & 7)) << 4) | within)) = f2bf(c);
                }
            }
        }
        __syncthreads();
#pragma unroll
        for (int it = 0; it < BM / 16; ++it) {
            int idx = it * 512 + t;
            int row = idx >> 5, ch = idx & 31;
            u16x8 v = *(const u16x8*)(clb + row * 512 + ((ch ^ (row & 7)) << 4));
            *(u16x8*)(outb + (size_t)(m0 + row) * NN + n0 + ch * 8) = v;
        }
    } else {
        const int rbase = m0 + wm * (BM / 2) + lg * 4;
        const int cbase = n0 + wn * 64 + lr;
#pragma unroll
        for (int n = 0; n < 4; ++n) {
            int col = cbase + n * 16;
            float bval = bias[col];
            float sval = scale[col];
#pragma unroll
            for (int m = 0; m < NFR; ++m) {
                int row = rbase + m * 16;
#pragma unroll
                for (int r = 0; r < 4; ++r) {
                    float c = acc[m][n][r] + bval;
                    size_t idx = (size_t)(row + r) * NN + col;
                    if (EPI == 1) {
                        float xv = (row + r < 8192) ? rx1[idx] : rx2[idx - (size_t)8192 * 1024];
                        outf[idx] = xv + sval * c;
                    } else {
                        outf[idx] += sval * c;
                    }
                }
            }
        }
    }
}

// ---------------------------------------------------------------------------
// Flash attention, MAX-FREE softmax (round-15 best): one block = (seq, head,
// 128-row Q tile), 8 waves, 2-slot LDS dbuf, XCD-affine balanced mapping.
// Scores bounded (|s*SC| << 128) -> P = exp2(s*SC) directly; per-lane partial
// row-sums reduced across the 16-lane group ONCE after the loop.
// T15: PV(kt) MFMA overlaps P-computation(kt+1) VALU.
// ---------------------------------------------------------------------------
__global__ __launch_bounds__(512) void attn_k(const unsigned short* __restrict__ qkv,
                                              const unsigned short* __restrict__ vT,
                                              unsigned short* __restrict__ aout) {
    __shared__ char sK[2][8192];
    __shared__ char sV[2][8192];
    __shared__ unsigned short sP[8][16 * 72];
    const int xcd = blockIdx.x & 7;
    const int idx = blockIdx.x >> 3;  // 0..191 per XCD
    int seq0, S, h, qt;
    if (idx < 128) {          // x1: seq = xcd; 16 heads x 8 qtiles
        h = idx & 15; qt = idx >> 4; seq0 = xcd << 10; S = 1024;
    } else {                  // x2: seq = xcd; 16 heads x 4 qtiles
        int j = idx - 128;
        h = j & 15; qt = j >> 4; seq0 = 8192 + (xcd << 9); S = 512;
    }
    int t = threadIdx.x, lane = t & 63, w = t >> 6, lr = lane & 15, lg = lane >> 4;
    int tok0 = seq0 + qt * 128;
    const size_t hoff = (size_t)h * 64;

    const int srow = t >> 3;
    const int sc = ((t & 7) ^ (srow & 7)) * 8;
    const unsigned short* kg = qkv + (size_t)(seq0 + srow) * 3072 + 1024 + hoff + sc;
    const unsigned short* vg = vT + (size_t)(hoff + srow) * 12288 + seq0 + sc;

    b16x8 aq0, aq1;
    {
        const unsigned short* qb = qkv + (size_t)(tok0 + w * 16 + lr) * 3072 + hoff;
        aq0 = *(const b16x8*)(qb + lg * 8);
        aq1 = *(const b16x8*)(qb + 32 + lg * 8);
    }

    auto STAGE = [&](int kt) {
        int slot = kt & 1;
        __builtin_amdgcn_global_load_lds(AS1C(kg + (size_t)(kt << 6) * 3072),
                                         AS3(sK[slot] + t * 16), 16, 0, 0);
        __builtin_amdgcn_global_load_lds(AS1C(vg + (kt << 6)),
                                         AS3(sV[slot] + t * 16), 16, 0, 0);
    };

    const int swz0 = (lg ^ (lr & 7)) * 16;
    const int swz1 = ((4 + lg) ^ (lr & 7)) * 16;
    const float SC = 0.18033688f;  // 0.125 * log2(e)

    float lsum[4] = {0.f, 0.f, 0.f, 0.f};
    f32x4 o[4] = {};
    unsigned short* sPw = sP[w];
    const int nkv = S >> 6;

    auto QK = [&](int kt, f32x4 (&s)[4]) {
        const char* kb = sK[kt & 1];
#pragma unroll
        for (int n = 0; n < 4; ++n) {
            const char* kr = kb + (n * 16 + lr) * 128;
            b16x8 bk0 = *(const b16x8*)(kr + swz0);
            b16x8 bk1 = *(const b16x8*)(kr + swz1);
            f32x4 z = {};
            z = __builtin_amdgcn_mfma_f32_16x16x32_bf16(aq0, bk0, z, 0, 0, 0);
            z = __builtin_amdgcn_mfma_f32_16x16x32_bf16(aq1, bk1, z, 0, 0, 0);
            s[n] = z * SC;
        }
    };
    // max-free: P = exp2(s), accumulate per-lane partial row sums, P->LDS->A-frags
    auto SM = [&](f32x4 (&s)[4], b16x8& a0, b16x8& a1) {
        float p[4][4];
#pragma unroll
        for (int n = 0; n < 4; ++n)
#pragma unroll
            for (int r = 0; r < 4; ++r)
                p[n][r] = exp2_f(s[n][r]);
#pragma unroll
        for (int r = 0; r < 4; ++r)
            lsum[r] += (p[0][r] + p[1][r]) + (p[2][r] + p[3][r]);
#pragma unroll
        for (int r = 0; r < 4; ++r)
#pragma unroll
            for (int n = 0; n < 4; ++n)
                sPw[(lg * 4 + r) * 72 + n * 16 + lr] = f2bf_trunc(p[n][r]);
        a0 = *(const b16x8*)(&sPw[lr * 72 + lg * 8]);
        a1 = *(const b16x8*)(&sPw[lr * 72 + 32 + lg * 8]);
    };

    // prologue: stage tiles 0,1; drain; QK+SM of tile 0.
    STAGE(0);
    if (nkv > 1) STAGE(1);
    asm volatile("s_waitcnt vmcnt(0)" ::: "memory");
    __builtin_amdgcn_s_barrier();
    FENCE();
    f32x4 s0[4];
    QK(0, s0);
    b16x8 ap0, ap1;
    SM(s0, ap0, ap1);

    for (int kt = 0; kt < nkv; ++kt) {
        // V(kt) -> regs (frees slot kt&1 after lgkmcnt drain)
        const char* vb = sV[kt & 1];
        b16x8 bv0[4], bv1[4];
#pragma unroll
        for (int n = 0; n < 4; ++n) {
            const char* vr = vb + (n * 16 + lr) * 128;
            bv0[n] = *(const b16x8*)(vr + swz0);
            bv1[n] = *(const b16x8*)(vr + swz1);
        }
        // QK of next tile (other slot)
        f32x4 s2[4];
        if (kt + 1 < nkv) QK(kt + 1, s2);
        // all LDS reads of slot kt must have completed before restaging it
        asm volatile("s_waitcnt lgkmcnt(0)" ::: "memory");
        __builtin_amdgcn_s_barrier();
        FENCE();
        if (kt + 2 < nkv) STAGE(kt + 2);
        // PV(kt) [MFMA, reg-only] overlapped with SM(kt+1) [VALU]
#pragma unroll
        for (int n = 0; n < 4; ++n) {
            o[n] = __builtin_amdgcn_mfma_f32_16x16x32_bf16(ap0, bv0[n], o[n], 0, 0, 0);
            o[n] = __builtin_amdgcn_mfma_f32_16x16x32_bf16(ap1, bv1[n], o[n], 0, 0, 0);
        }
        if (kt + 1 < nkv) {
            SM(s2, ap0, ap1);
            asm volatile("s_waitcnt vmcnt(0)" ::: "memory");
            __builtin_amdgcn_s_barrier();
            FENCE();
        }
    }
    // final: reduce row sums across the 16-lane group (once), then output.
#pragma unroll
    for (int r = 0; r < 4; ++r) {
        lsum[r] += __shfl_xor(lsum[r], 1);
        lsum[r] += __shfl_xor(lsum[r], 2);
        lsum[r] += __shfl_xor(lsum[r], 4);
        lsum[r] += __shfl_xor(lsum[r], 8);
    }
    __syncthreads();
    char* ob = sK[0];
#pragma unroll
    for (int r = 0; r < 4; ++r) {
        float inv = __builtin_amdgcn_rcpf(lsum[r]);
        const int row_l = w * 16 + lg * 4 + r;
#pragma unroll
        for (int n = 0; n < 4; ++n) {
            const int colByte = (n * 16 + lr) * 2;
            *(unsigned short*)(ob + row_l * 128 +
                               ((((colByte >> 4) ^ (row_l & 7)) << 4) | (colByte & 15))) =
                f2bf(o[n][r] * inv);
        }
    }
    __syncthreads();
#pragma unroll
    for (int it = 0; it < 2; ++it) {
        int idx2 = it * 512 + t;
        int row = idx2 >> 3, ch = idx2 & 7;
        u16x8 v = *(const u16x8*)(ob + row * 128 + ((ch ^ (row & 7)) << 4));
        *(u16x8*)(aout + (size_t)(tok0 + row) * 1024 + hoff + ch * 8) = v;
    }
}

// ---------------------------------------------------------------------------
// Launch
// ---------------------------------------------------------------------------
extern "C" void kernel_launch(void* const* d_in, const int* in_sizes, int n_in,
                              void* d_out, int out_size, void* d_ws, size_t ws_size,
                              hipStream_t stream) {
    const float* x1     = (const float*)d_in[0];
    const float* x2     = (const float*)d_in[1];
    const float* w_qkv  = (const float*)d_in[2];
    const float* b_qkv  = (const float*)d_in[3];
    const float* w_proj = (const float*)d_in[4];
    const float* b_proj = (const float*)d_in[5];
    const float* ln1w   = (const float*)d_in[6];
    const float* ln1b   = (const float*)d_in[7];
    const float* ln2w   = (const float*)d_in[8];
    const float* ln2b   = (const float*)d_in[9];
    const float* w_fc1  = (const float*)d_in[10];
    const float* b_fc1  = (const float*)d_in[11];
    const float* w_fc2  = (const float*)d_in[12];
    const float* b_fc2  = (const float*)d_in[13];
    const float* gamma1 = (const float*)d_in[14];
    const float* gamma2 = (const float*)d_in[15];
    float* out = (float*)d_out;
    char* ws = (char*)d_ws;

    // Workspace layout (144 MiB total)
    unsigned short* wqkvT  = (unsigned short*)(ws);              //  6291456 B
    unsigned short* wprojT = (unsigned short*)(ws + 6291456);    //  2097152 B
    unsigned short* wfc1T  = (unsigned short*)(ws + 8388608);    //  8388608 B
    unsigned short* wfc2T  = (unsigned short*)(ws + 16777216);   //  8388608 B
    unsigned short* lnbuf  = (unsigned short*)(ws + 25165824);   // 25165824 B (also vT later)
    unsigned short* qkvbuf = (unsigned short*)(ws + 50331648);   // 75497472 B
    unsigned short* attnbuf= (unsigned short*)(ws + 125829120);  // 25165824 B
    unsigned short* actbuf = (unsigned short*)(ws + 50331648);   // aliases qkv+attn (dead by then)
    unsigned short* vTbuf  = lnbuf;                              // 1024 x 12288 bf16

    wtrans_k<<<dim3(96, 32), 256, 0, stream>>>(w_qkv, wqkvT, 1024, 3072);
    wtrans_k<<<dim3(32, 32), 256, 0, stream>>>(w_proj, wprojT, 1024, 1024);
    wtrans_k<<<dim3(128, 32), 256, 0, stream>>>(w_fc1, wfc1T, 1024, 4096);
    wtrans_k<<<dim3(32, 128), 256, 0, stream>>>(w_fc2, wfc2T, 4096, 1024);
    ln_k<<<12288, 256, 0, stream>>>(x1, x2, 8192, ln1w, ln1b, lnbuf);
    // qkv: 64 m-tiles x 12 n-tiles = 768 blocks (3 exact CU rounds)
    gemm3_k<192, 1024, 3072, 0><<<768, 512, 0, stream>>>(lnbuf, wqkvT, b_qkv, nullptr,
                                                         nullptr, nullptr, nullptr, qkvbuf);
    vtrans_k<<<dim3(384, 32), 256, 0, stream>>>(qkvbuf, vTbuf);
    attn_k<<<1536, 512, 0, stream>>>(qkvbuf, vTbuf, attnbuf);
    // proj: 64 x 4 = 256 blocks (1 exact round)
    gemm3_k<192, 1024, 1024, 1><<<256, 512, 0, stream>>>(attnbuf, wprojT, b_proj, gamma1,
                                                         x1, x2, out, nullptr);
    ln_k<<<12288, 256, 0, stream>>>(out, out + (size_t)8192 * 1024, 8192, ln2w, ln2b, lnbuf);
    // fc1: BM=256 -> 48 x 16 = 768 blocks (3 exact rounds)
    gemm3_k<256, 1024, 4096, 2><<<768, 512, 0, stream>>>(lnbuf, wfc1T, b_fc1, nullptr,
                                                         nullptr, nullptr, nullptr, actbuf);
    // fc2: 64 x 4 = 256 blocks (1 exact round)
    gemm3_k<192, 4096, 1024, 3><<<256, 512, 0, stream>>>(actbuf, wfc2T, b_fc2, gamma2,
                                                         nullptr, nullptr, out, nullptr);
}